// Round 6
// baseline (280.170 us; speedup 1.0000x reference)
//
#include <hip/hip_runtime.h>
#include <math.h>

#define B_   32
#define M_   32
#define P_   196
#define D_   20
#define O_   16
#define I_   8
#define DO_  320    // D*O
#define PD_  3920   // P*D
#define ROW_ 62720  // P*DO

#define CMAPS_OFF 10240
#define FEAT_OFF  4024320

__device__ __forceinline__ unsigned short f2bf(float v) {
    unsigned int u = __float_as_uint(v);
    return (unsigned short)((u + 0x7fffu + ((u >> 16) & 1u)) >> 16);
}
__device__ __forceinline__ unsigned int pk2(float lo, float hi) {
    return (unsigned int)f2bf(lo) | ((unsigned int)f2bf(hi) << 16);
}
__device__ __forceinline__ float bfhi(unsigned int w) { return __uint_as_float(w & 0xffff0000u); }
__device__ __forceinline__ float bflo(unsigned int w) { return __uint_as_float(w << 16); }

// async global->LDS, 16B per lane; lds ptr must be wave-uniform base
__device__ __forceinline__ void gload16(const float* g, float* l) {
    __builtin_amdgcn_global_load_lds(
        (const __attribute__((address_space(1))) void*)g,
        (__attribute__((address_space(3))) void*)l, 16, 0, 0);
}

// ---------------- K1: u_hat = W.x -> bf16, fused s1 atomics ----------------
// grid M*98 (p-tiles of 2), 320 threads. W staged per-pl (10KB), double-
// buffered; one mid-kernel barrier. Source-swizzled (s ^ ((s>>4)&7)).
// thread: g=t%40 owns do {2g+80r, +1}, r=0..3 ; bq=t/40 owns b = bq*4+bb.
// s1 partial (sum over this block's 2 p's) atomicAdd'ed into s1r replica.
#define CPT_ 2
#define CNT_ 98
__global__ __launch_bounds__(320)
void caps_u(const float* __restrict__ x, const float* __restrict__ W,
            unsigned short* __restrict__ uh, float* __restrict__ s1r)
{
    __shared__ float4 wb[2][640];        // 2 x 10,240 B (1 pl each)
    __shared__ float  xl[512];           // [b][p][i]

    const int m  = blockIdx.x / CNT_;
    const int pt = blockIdx.x % CNT_;
    const int p0 = pt * CPT_;
    const int t  = threadIdx.x;
    const int g  = t % 40;
    const int bq = t / 40;
    const int wl = t & ~63;              // wave-uniform slot base

    if (t < 128) {
        int b = t >> 2, q = t & 3;       // p = q>>1, half = q&1
        *(float4*)(xl + b * 16 + q * 4) =
            *(const float4*)(x + (((size_t)b * M_ + m) * P_ + p0 + (q >> 1)) * I_
                             + (q & 1) * 4);
    }
    {   // prologue: stage pl=0 (640 slots in 2 rounds)
        const float* ws0 = W + (size_t)(m * P_ + p0) * 2560;
        #pragma unroll
        for (int q = 0; q < 2; q++) {
            int s = q * 320 + t;
            gload16(ws0 + (size_t)(s ^ ((s >> 4) & 7)) * 4,
                    (float*)&wb[0][q * 320 + wl]);
        }
    }
    __syncthreads();

    float acc_s[4][4][2];                // [bb][r][lo/hi] s1 partials
    #pragma unroll
    for (int bb = 0; bb < 4; bb++)
        #pragma unroll
        for (int r = 0; r < 4; r++) { acc_s[bb][r][0] = 0.f; acc_s[bb][r][1] = 0.f; }

    #pragma unroll
    for (int h = 0; h < 2; h++) {
        if (h == 0) {                    // prefetch pl=1
            const float* ws1 = W + (size_t)(m * P_ + p0 + 1) * 2560;
            #pragma unroll
            for (int q = 0; q < 2; q++) {
                int s = q * 320 + t;
                gload16(ws1 + (size_t)(s ^ ((s >> 4) & 7)) * 4,
                        (float*)&wb[1][q * 320 + wl]);
            }
        }
        const int pl = h;
        float xr[4][8];
        #pragma unroll
        for (int bb = 0; bb < 4; bb++) {
            *(float4*)(xr[bb])     = *(float4*)(xl + (bq * 4 + bb) * 16 + pl * 8);
            *(float4*)(xr[bb] + 4) = *(float4*)(xl + (bq * 4 + bb) * 16 + pl * 8 + 4);
        }
        const float4* wp = wb[h];
        #pragma unroll
        for (int r = 0; r < 4; r++) {
            const int gb = 4 * g + 160 * r;
            const int hx = (gb >> 4) & 7;
            float4 w0 = wp[(gb + 0) ^ hx];
            float4 w1 = wp[(gb + 1) ^ hx];
            float4 w2 = wp[(gb + 2) ^ hx];
            float4 w3 = wp[(gb + 3) ^ hx];
            const int do0 = 2 * g + 80 * r;
            #pragma unroll
            for (int bb = 0; bb < 4; bb++) {
                const float* a = xr[bb];
                float u0 = w0.x * a[0];
                u0 = fmaf(w0.y, a[1], u0); u0 = fmaf(w0.z, a[2], u0);
                u0 = fmaf(w0.w, a[3], u0); u0 = fmaf(w1.x, a[4], u0);
                u0 = fmaf(w1.y, a[5], u0); u0 = fmaf(w1.z, a[6], u0);
                u0 = fmaf(w1.w, a[7], u0);
                float u1 = w2.x * a[0];
                u1 = fmaf(w2.y, a[1], u1); u1 = fmaf(w2.z, a[2], u1);
                u1 = fmaf(w2.w, a[3], u1); u1 = fmaf(w3.x, a[4], u1);
                u1 = fmaf(w3.y, a[5], u1); u1 = fmaf(w3.z, a[6], u1);
                u1 = fmaf(w3.w, a[7], u1);
                acc_s[bb][r][0] += u0; acc_s[bb][r][1] += u1;
                *(unsigned int*)(uh + (((size_t)(bq * 4 + bb) * M_ + m) * P_
                                       + p0 + pl) * DO_ + do0) = pk2(u0, u1);
            }
        }
        if (h == 0) __syncthreads();     // buf1 ready; covered by pl0 compute
    }
    // fused s1: one atomic per owned cell (unique per thread within block)
    float* s1p = s1r + (blockIdx.x & 3) * (B_ * DO_);
    #pragma unroll
    for (int bb = 0; bb < 4; bb++) {
        const int b = bq * 4 + bb;
        #pragma unroll
        for (int r = 0; r < 4; r++) {
            const int do0 = 2 * g + 80 * r;
            atomicAdd(s1p + b * DO_ + do0,     acc_s[bb][r][0]);
            atomicAdd(s1p + b * DO_ + do0 + 1, acc_s[bb][r][1]);
        }
    }
}

// ---------------- route: one block per (b,m) row of u_hat ----------------
// MODE 1: online-softmax s partial (blog=u.v). MODE 2: + c_maps + features.
// thread: d=t%20, chunk k=t/20 over P. unroll-2, depth-2 prefetch.
template<int MODE>
__global__ __launch_bounds__(320)
void route_k(const unsigned short* __restrict__ uh, const float* __restrict__ vin,
             float* __restrict__ pbm, float* __restrict__ out)
{
    extern __shared__ float sm[];
    float* accL  = sm;               // [320*17]
    float* red   = sm + 320 * 17;    // [16]
    float* blogL = red + 16;         // [3920] (MODE2)
    float* usqL  = blogL + 3920;     // [3920] (MODE2)

    const int blk = blockIdx.x;      // b*32 + m
    const int t = threadIdx.x;
    const int d = t % 20;
    const int k = t / 20;
    const int pstart = k * 12 + (k < 4 ? k : 4);
    const int pcnt   = (k < 4) ? 13 : 12;
    const unsigned short* up = uh + (size_t)blk * ROW_ + d * 16;

    float vreg[16];
    {
        const float* vb = vin + (size_t)(blk >> 5) * DO_;
        #pragma unroll
        for (int o = 0; o < 16; o++) vreg[o] = vb[d * 16 + o];
    }
    float acc[16];
    #pragma unroll
    for (int o = 0; o < 16; o++) acc[o] = 0.f;
    float mloc = -1e30f, Z = 0.f;

    float4 c0a, c0b, c1a, c1b;
    c0a = ((const float4*)(up + (size_t)pstart * DO_))[0];
    c0b = ((const float4*)(up + (size_t)pstart * DO_))[1];
    {
        int p1 = pstart + (pcnt > 1 ? 1 : 0);
        c1a = ((const float4*)(up + (size_t)p1 * DO_))[0];
        c1b = ((const float4*)(up + (size_t)p1 * DO_))[1];
    }

#define PROC(A0, A1, PIDX)                                                    \
    {                                                                         \
        unsigned int ua[8];                                                   \
        ua[0]=__float_as_uint(A0.x); ua[1]=__float_as_uint(A0.y);             \
        ua[2]=__float_as_uint(A0.z); ua[3]=__float_as_uint(A0.w);             \
        ua[4]=__float_as_uint(A1.x); ua[5]=__float_as_uint(A1.y);             \
        ua[6]=__float_as_uint(A1.z); ua[7]=__float_as_uint(A1.w);             \
        float u[16];                                                          \
        _Pragma("unroll")                                                     \
        for (int q = 0; q < 8; q++) { u[2*q] = bflo(ua[q]); u[2*q+1] = bfhi(ua[q]); } \
        float bl = u[0] * vreg[0];                                            \
        _Pragma("unroll")                                                     \
        for (int o = 1; o < 16; o++) bl = fmaf(u[o], vreg[o], bl);            \
        if (MODE == 2) {                                                      \
            float us = u[0] * u[0];                                           \
            _Pragma("unroll")                                                 \
            for (int o = 1; o < 16; o++) us = fmaf(u[o], u[o], us);           \
            blogL[(PIDX) * D_ + d] = bl;                                      \
            usqL[(PIDX) * D_ + d]  = us;                                      \
        }                                                                     \
        if (bl > mloc + 8.f) {                                                \
            float rr = __expf(mloc - bl);                                     \
            Z *= rr;                                                          \
            _Pragma("unroll")                                                 \
            for (int o = 0; o < 16; o++) acc[o] *= rr;                        \
            mloc = bl;                                                        \
        }                                                                     \
        float e = __expf(bl - mloc);                                          \
        Z += e;                                                               \
        _Pragma("unroll")                                                     \
        for (int o = 0; o < 16; o++) acc[o] = fmaf(e, u[o], acc[o]);          \
    }

    int pp = 0;
    for (; pp + 1 < pcnt; pp += 2) {
        int pn0 = pstart + ((pp + 2 < pcnt) ? pp + 2 : pcnt - 1);
        int pn1 = pstart + ((pp + 3 < pcnt) ? pp + 3 : pcnt - 1);
        float4 n0a = ((const float4*)(up + (size_t)pn0 * DO_))[0];
        float4 n0b = ((const float4*)(up + (size_t)pn0 * DO_))[1];
        float4 n1a = ((const float4*)(up + (size_t)pn1 * DO_))[0];
        float4 n1b = ((const float4*)(up + (size_t)pn1 * DO_))[1];
        PROC(c0a, c0b, pstart + pp);
        PROC(c1a, c1b, pstart + pp + 1);
        c0a = n0a; c0b = n0b; c1a = n1a; c1b = n1b;
    }
    if (pp < pcnt) PROC(c0a, c0b, pstart + pp);
#undef PROC

    float f, iz, mx;
    {
        mx = mloc;
        #pragma unroll
        for (int msk = 1; msk < 64; msk <<= 1) mx = fmaxf(mx, __shfl_xor(mx, msk, 64));
        if ((t & 63) == 0) red[t >> 6] = mx;
        __syncthreads();
        mx = fmaxf(fmaxf(fmaxf(red[0], red[1]), fmaxf(red[2], red[3])), red[4]);
        f = __expf(mloc - mx);
        float zz = Z * f;
        #pragma unroll
        for (int msk = 1; msk < 64; msk <<= 1) zz += __shfl_xor(zz, msk, 64);
        if ((t & 63) == 0) red[8 + (t >> 6)] = zz;
        __syncthreads();
        iz = 1.f / (red[8] + red[9] + red[10] + red[11] + red[12]);
    }
    #pragma unroll
    for (int o = 0; o < 16; o++) accL[t * 17 + o] = acc[o] * f;
    __syncthreads();
    {
        const int dd = t >> 4, oo = t & 15;
        float s = 0.f;
        #pragma unroll
        for (int kk = 0; kk < 16; kk++) s += accL[(kk * 20 + dd) * 17 + oo];
        s *= iz;
        pbm[(size_t)blk * DO_ + t] = s;
        if (MODE == 2) out[FEAT_OFF + (size_t)blk * DO_ + t] = s * (1.f / 196.f);
    }
    if (MODE == 2) {
        for (int e = t; e < PD_; e += 320)
            out[CMAPS_OFF + (size_t)blk * PD_ + e] =
                __expf(blogL[e] - mx) * iz * sqrtf(usqL[e]);
    }
}

// ---------------- squash ----------------
// WH 0: s from s1r replicas (scale 1/PD) -> v1. WH 1: vs = v1 + v2.
// WH 2: v -> out.
template<int WH>
__global__ __launch_bounds__(320)
void sq2_k(const float* __restrict__ src, float* __restrict__ v1,
           float* __restrict__ vs, float* __restrict__ out)
{
    const int b = blockIdx.x, t = threadIdx.x;
    float s = 0.f;
    if (WH == 0) {
        #pragma unroll
        for (int rep = 0; rep < 4; rep++)
            s += src[rep * (B_ * DO_) + b * DO_ + t];
        s *= (1.f / PD_);
    } else {
        for (int mi = 0; mi < M_; mi++) s += src[((size_t)b * M_ + mi) * DO_ + t];
    }
    float sq = s * s;
    #pragma unroll
    for (int msk = 1; msk < 16; msk <<= 1) sq += __shfl_xor(sq, msk, 16);
    float vr = (sq / (1.f + sq)) * s * rsqrtf(sq + 1e-9f);
    if (WH == 0) v1[(size_t)b * DO_ + t] = vr;
    if (WH == 1) vs[(size_t)b * DO_ + t] = v1[(size_t)b * DO_ + t] + vr;
    if (WH == 2) out[(size_t)b * DO_ + t] = vr;
}

extern "C" void kernel_launch(void* const* d_in, const int* in_sizes, int n_in,
                              void* d_out, int out_size, void* d_ws, size_t ws_size,
                              hipStream_t stream)
{
    const float* x = (const float*)d_in[0];
    const float* W = (const float*)d_in[1];
    float* out = (float*)d_out;

    unsigned short* uh = (unsigned short*)d_ws;   // bf16 u_hat: 128,450,560 B
    float* fws = (float*)((char*)d_ws + (size_t)64225280 * 2);
    float* pbm = fws;                             // [B][M][DO] = 327,680 fl
    float* v1  = pbm + (size_t)B_ * M_ * DO_;     // 10,240 fl
    float* vs  = v1 + (size_t)B_ * DO_;           // 10,240 fl
    float* s1r = vs + (size_t)B_ * DO_;           // 4 x 10,240 fl

    const size_t LDS_A = (320 * 17 + 16) * sizeof(float);
    const size_t LDS_B = LDS_A + 2 * PD_ * sizeof(float);

    hipMemsetAsync(s1r, 0, 4 * (size_t)B_ * DO_ * sizeof(float), stream);

    caps_u<<<M_ * CNT_, 320, 0, stream>>>(x, W, uh, s1r);
    sq2_k<0><<<B_, 320, 0, stream>>>(s1r, v1, vs, out);

    route_k<1><<<B_ * M_, 320, LDS_A, stream>>>(uh, v1, pbm, out);
    sq2_k<1><<<B_, 320, 0, stream>>>(pbm, v1, vs, out);

    route_k<2><<<B_ * M_, 320, LDS_B, stream>>>(uh, vs, pbm, out);
    sq2_k<2><<<B_, 320, 0, stream>>>(pbm, v1, vs, out);
}

// Round 8
// 163.546 us; speedup vs baseline: 1.7131x; 1.7131x over previous
//
#include <hip/hip_runtime.h>
#include <math.h>

#define B_   32
#define M_   32
#define P_   196
#define D_   20
#define O_   16
#define I_   8
#define DO_  320    // D*O
#define PD_  3920   // P*D
#define ROW_ 62720  // P*DO

#define CMAPS_OFF 10240
#define FEAT_OFF  4024320

typedef float nf4 __attribute__((ext_vector_type(4)));   // native vec for NT builtins

__device__ __forceinline__ unsigned short f2bf(float v) {
    unsigned int u = __float_as_uint(v);
    return (unsigned short)((u + 0x7fffu + ((u >> 16) & 1u)) >> 16);
}
__device__ __forceinline__ unsigned int pk2(float lo, float hi) {
    return (unsigned int)f2bf(lo) | ((unsigned int)f2bf(hi) << 16);
}
__device__ __forceinline__ float bfhi(unsigned int w) { return __uint_as_float(w & 0xffff0000u); }
__device__ __forceinline__ float bflo(unsigned int w) { return __uint_as_float(w << 16); }

// async global->LDS, 16B per lane; lds ptr must be wave-uniform base
__device__ __forceinline__ void gload16(const float* g, float* l) {
    __builtin_amdgcn_global_load_lds(
        (const __attribute__((address_space(1))) void*)g,
        (__attribute__((address_space(3))) void*)l, 16, 0, 0);
}

// ---------------- K1: u_hat = W.x -> bf16 ----------------
// grid M*49 (p-tiles of 4), 320 threads. W staged in 2-pl halves (20KB),
// double-buffered; one mid-kernel barrier. Source-swizzled (s ^ ((s>>4)&7)).
// uh stores are NON-TEMPORAL (streaming, no L2 allocation).
#define CPT_ 4
#define CNT_ 49
__global__ __launch_bounds__(320)
void caps_u(const float* __restrict__ x, const float* __restrict__ W,
            unsigned short* __restrict__ uh)
{
    __shared__ float4 wb[2][1280];       // 2 x 20,480 B (2 pl each)
    __shared__ float  xl[1024];          // [b][pl*8+i]

    const int m  = blockIdx.x / CNT_;
    const int pt = blockIdx.x % CNT_;
    const int p0 = pt * CPT_;
    const int t  = threadIdx.x;
    const int g  = t % 40;
    const int bq = t / 40;
    const int wl = t & ~63;              // wave-uniform slot base

    if (t < 256) {
        int b = t >> 3, q = t & 7;
        *(float4*)(xl + b * 32 + q * 4) =
            *(const float4*)(x + (((size_t)b * M_ + m) * P_ + p0) * I_ + q * 4);
    }
    {   // prologue: stage half 0 (pl 0,1) = 1280 slots in 4 rounds
        const float* ws0 = W + (size_t)(m * P_ + p0) * 2560;
        #pragma unroll
        for (int q = 0; q < 4; q++) {
            int s = q * 320 + t;
            gload16(ws0 + (size_t)(s ^ ((s >> 4) & 7)) * 4,
                    (float*)&wb[0][q * 320 + wl]);
        }
    }
    __syncthreads();

    #pragma unroll
    for (int h = 0; h < 2; h++) {
        if (h == 0) {                    // prefetch half 1 (pl 2,3)
            const float* ws1 = W + (size_t)(m * P_ + p0 + 2) * 2560;
            #pragma unroll
            for (int q = 0; q < 4; q++) {
                int s = q * 320 + t;
                gload16(ws1 + (size_t)(s ^ ((s >> 4) & 7)) * 4,
                        (float*)&wb[1][q * 320 + wl]);
            }
        }
        #pragma unroll
        for (int pp = 0; pp < 2; pp++) {
            const int pl = 2 * h + pp;
            float xr[4][8];
            #pragma unroll
            for (int bb = 0; bb < 4; bb++) {
                *(float4*)(xr[bb])     = *(float4*)(xl + (bq * 4 + bb) * 32 + pl * 8);
                *(float4*)(xr[bb] + 4) = *(float4*)(xl + (bq * 4 + bb) * 32 + pl * 8 + 4);
            }
            const float4* wp = &wb[h][pp * 640];
            #pragma unroll
            for (int r = 0; r < 4; r++) {
                const int gb = 4 * g + 160 * r;
                const int hx = (gb >> 4) & 7;
                float4 w0 = wp[(gb + 0) ^ hx];
                float4 w1 = wp[(gb + 1) ^ hx];
                float4 w2 = wp[(gb + 2) ^ hx];
                float4 w3 = wp[(gb + 3) ^ hx];
                const int do0 = 2 * g + 80 * r;
                #pragma unroll
                for (int bb = 0; bb < 4; bb++) {
                    const float* a = xr[bb];
                    float u0 = w0.x * a[0];
                    u0 = fmaf(w0.y, a[1], u0); u0 = fmaf(w0.z, a[2], u0);
                    u0 = fmaf(w0.w, a[3], u0); u0 = fmaf(w1.x, a[4], u0);
                    u0 = fmaf(w1.y, a[5], u0); u0 = fmaf(w1.z, a[6], u0);
                    u0 = fmaf(w1.w, a[7], u0);
                    float u1 = w2.x * a[0];
                    u1 = fmaf(w2.y, a[1], u1); u1 = fmaf(w2.z, a[2], u1);
                    u1 = fmaf(w2.w, a[3], u1); u1 = fmaf(w3.x, a[4], u1);
                    u1 = fmaf(w3.y, a[5], u1); u1 = fmaf(w3.z, a[6], u1);
                    u1 = fmaf(w3.w, a[7], u1);
                    unsigned int* dst = (unsigned int*)(uh +
                        (((size_t)(bq * 4 + bb) * M_ + m) * P_ + p0 + pl) * DO_ + do0);
                    __builtin_nontemporal_store(pk2(u0, u1), dst);
                }
            }
        }
        if (h == 0) __syncthreads();     // buf1 ready; covered by half-0 compute
    }
}

// ---------------- route: one block per (b,m) row of u_hat ----------------
// MODE 0: s1 partial (uniform c). MODE 1: online-softmax s partial (blog=u.v)
// MODE 2: same + c_maps + features. thread: d=t%20, chunk k=t/20 over P.
// uh stream: prefetch-by-1, NON-TEMPORAL loads.
template<int MODE>
__global__ __launch_bounds__(320)
void route_k(const unsigned short* __restrict__ uh, const float* __restrict__ vin,
             float* __restrict__ pbm, float* __restrict__ out)
{
    extern __shared__ float sm[];
    float* accL  = sm;               // [320*17]
    float* red   = sm + 320 * 17;    // [16]
    float* blogL = red + 16;         // [3920] (MODE2)
    float* usqL  = blogL + 3920;     // [3920] (MODE2)

    const int blk = blockIdx.x;      // b*32 + m
    const int t = threadIdx.x;
    const int d = t % 20;
    const int k = t / 20;
    const int pstart = k * 12 + (k < 4 ? k : 4);
    const int pcnt   = (k < 4) ? 13 : 12;
    const unsigned short* up = uh + (size_t)blk * ROW_ + d * 16;

    float vreg[16];
    if (MODE) {
        const float* vb = vin + (size_t)(blk >> 5) * DO_;
        #pragma unroll
        for (int o = 0; o < 16; o++) vreg[o] = vb[d * 16 + o];
    }
    float acc[16];
    #pragma unroll
    for (int o = 0; o < 16; o++) acc[o] = 0.f;
    float mloc = -1e30f, Z = 0.f;

    nf4 a0 = __builtin_nontemporal_load((const nf4*)(up + (size_t)pstart * DO_));
    nf4 a1 = __builtin_nontemporal_load((const nf4*)(up + (size_t)pstart * DO_) + 1);

    for (int pp = 0; pp < pcnt; pp++) {
        const int p  = pstart + pp;
        const int pn = pstart + ((pp + 1 < pcnt) ? pp + 1 : pp);
        nf4 n0 = __builtin_nontemporal_load((const nf4*)(up + (size_t)pn * DO_));
        nf4 n1 = __builtin_nontemporal_load((const nf4*)(up + (size_t)pn * DO_) + 1);

        unsigned int ua[8];
        ua[0]=__float_as_uint(a0.x); ua[1]=__float_as_uint(a0.y);
        ua[2]=__float_as_uint(a0.z); ua[3]=__float_as_uint(a0.w);
        ua[4]=__float_as_uint(a1.x); ua[5]=__float_as_uint(a1.y);
        ua[6]=__float_as_uint(a1.z); ua[7]=__float_as_uint(a1.w);
        float u[16];
        #pragma unroll
        for (int q = 0; q < 8; q++) { u[2*q] = bflo(ua[q]); u[2*q+1] = bfhi(ua[q]); }

        if (MODE) {
            float bl = u[0] * vreg[0];
            #pragma unroll
            for (int o = 1; o < 16; o++) bl = fmaf(u[o], vreg[o], bl);
            if (MODE == 2) {
                float us = u[0] * u[0];
                #pragma unroll
                for (int o = 1; o < 16; o++) us = fmaf(u[o], u[o], us);
                blogL[p * D_ + d] = bl;
                usqL[p * D_ + d]  = us;
            }
            if (bl > mloc + 8.f) {           // defer-max rescale (T13)
                float r = __expf(mloc - bl);
                Z *= r;
                #pragma unroll
                for (int o = 0; o < 16; o++) acc[o] *= r;
                mloc = bl;
            }
            float e = __expf(bl - mloc);
            Z += e;
            #pragma unroll
            for (int o = 0; o < 16; o++) acc[o] = fmaf(e, u[o], acc[o]);
        } else {
            #pragma unroll
            for (int o = 0; o < 16; o++) acc[o] += u[o];
        }
        a0 = n0; a1 = n1;
    }

    float f = 1.f, iz = 1.f, mx = 0.f;
    if (MODE) {
        mx = mloc;
        #pragma unroll
        for (int msk = 1; msk < 64; msk <<= 1) mx = fmaxf(mx, __shfl_xor(mx, msk, 64));
        if ((t & 63) == 0) red[t >> 6] = mx;
        __syncthreads();
        mx = fmaxf(fmaxf(fmaxf(red[0], red[1]), fmaxf(red[2], red[3])), red[4]);
        f = __expf(mloc - mx);
        float zz = Z * f;
        #pragma unroll
        for (int msk = 1; msk < 64; msk <<= 1) zz += __shfl_xor(zz, msk, 64);
        if ((t & 63) == 0) red[8 + (t >> 6)] = zz;
        __syncthreads();
        iz = 1.f / (red[8] + red[9] + red[10] + red[11] + red[12]);
    }
    #pragma unroll
    for (int o = 0; o < 16; o++) accL[t * 17 + o] = acc[o] * f;
    __syncthreads();
    {
        const int dd = t >> 4, oo = t & 15;
        float s = 0.f;
        #pragma unroll
        for (int kk = 0; kk < 16; kk++) s += accL[(kk * 20 + dd) * 17 + oo];
        s *= iz;
        pbm[(size_t)blk * DO_ + t] = s;
        if (MODE == 2) out[FEAT_OFF + (size_t)blk * DO_ + t] = s * (1.f / 196.f);
    }
    if (MODE == 2) {
        for (int e = t; e < PD_; e += 320)
            out[CMAPS_OFF + (size_t)blk * PD_ + e] =
                __expf(blogL[e] - mx) * iz * sqrtf(usqL[e]);
    }
}

// ---------------- squash: per b, sum partials over m ----------------
template<int WH>
__global__ __launch_bounds__(320)
void sq2_k(const float* __restrict__ pbm, float* __restrict__ v1,
           float* __restrict__ vs, float* __restrict__ out)
{
    const int b = blockIdx.x, t = threadIdx.x;
    float s = 0.f;
    for (int mi = 0; mi < M_; mi++) s += pbm[((size_t)b * M_ + mi) * DO_ + t];
    if (WH == 0) s *= (1.f / PD_);
    float sq = s * s;
    #pragma unroll
    for (int msk = 1; msk < 16; msk <<= 1) sq += __shfl_xor(sq, msk, 16);
    float vr = (sq / (1.f + sq)) * s * rsqrtf(sq + 1e-9f);
    if (WH == 0) v1[(size_t)b * DO_ + t] = vr;
    if (WH == 1) vs[(size_t)b * DO_ + t] = v1[(size_t)b * DO_ + t] + vr;
    if (WH == 2) out[(size_t)b * DO_ + t] = vr;
}

extern "C" void kernel_launch(void* const* d_in, const int* in_sizes, int n_in,
                              void* d_out, int out_size, void* d_ws, size_t ws_size,
                              hipStream_t stream)
{
    const float* x = (const float*)d_in[0];
    const float* W = (const float*)d_in[1];
    float* out = (float*)d_out;

    unsigned short* uh = (unsigned short*)d_ws;   // bf16 u_hat: 128,450,560 B
    float* fws = (float*)((char*)d_ws + (size_t)64225280 * 2);
    float* pbm = fws;                             // [B][M][DO]
    float* v1  = pbm + (size_t)B_ * M_ * DO_;
    float* vs  = v1 + (size_t)B_ * DO_;

    const size_t LDS_A = (320 * 17 + 16) * sizeof(float);
    const size_t LDS_B = LDS_A + 2 * PD_ * sizeof(float);

    caps_u<<<M_ * CNT_, 320, 0, stream>>>(x, W, uh);

    route_k<0><<<B_ * M_, 320, LDS_A, stream>>>(uh, v1, pbm, out);
    sq2_k<0><<<B_, 320, 0, stream>>>(pbm, v1, vs, out);

    route_k<1><<<B_ * M_, 320, LDS_A, stream>>>(uh, v1, pbm, out);
    sq2_k<1><<<B_, 320, 0, stream>>>(pbm, v1, vs, out);

    route_k<2><<<B_ * M_, 320, LDS_B, stream>>>(uh, vs, pbm, out);
    sq2_k<2><<<B_, 320, 0, stream>>>(pbm, v1, vs, out);
}

// Round 9
// 117.105 us; speedup vs baseline: 2.3925x; 1.3966x over previous
//
#include <hip/hip_runtime.h>
#include <math.h>

#define B_   32
#define M_   32
#define P_   196
#define D_   20
#define O_   16
#define I_   8
#define DO_  320    // D*O
#define PD_  3920   // P*D
#define ROW_ 62720  // P*DO

#define CMAPS_OFF 10240
#define FEAT_OFF  4024320

__device__ __forceinline__ unsigned short f2bf(float v) {
    unsigned int u = __float_as_uint(v);
    return (unsigned short)((u + 0x7fffu + ((u >> 16) & 1u)) >> 16);
}
__device__ __forceinline__ unsigned int pk2(float lo, float hi) {
    return (unsigned int)f2bf(lo) | ((unsigned int)f2bf(hi) << 16);
}
__device__ __forceinline__ float bfhi(unsigned int w) { return __uint_as_float(w & 0xffff0000u); }
__device__ __forceinline__ float bflo(unsigned int w) { return __uint_as_float(w << 16); }

// async global->LDS, 16B per lane; lds ptr must be wave-uniform base
__device__ __forceinline__ void gload16(const float* g, float* l) {
    __builtin_amdgcn_global_load_lds(
        (const __attribute__((address_space(1))) void*)g,
        (__attribute__((address_space(3))) void*)l, 16, 0, 0);
}

// ---------------- K1: u_hat = W.x -> bf16 ----------------
// grid M*98 (p-tiles of 2), 320 threads. LDS 22.5KB -> 6 blocks/CU.
// W staged per-pl (10KB), double-buffered; one mid-kernel barrier.
// Source-swizzled (s ^ ((s>>4)&7)) so ds reads are ~conflict-free.
// thread: g=t%40 owns do {2g+80r, +1}, r=0..3 ; bq=t/40 owns b = bq*4+bb.
#define CPT_ 2
#define CNT_ 98
__global__ __launch_bounds__(320)
void caps_u(const float* __restrict__ x, const float* __restrict__ W,
            unsigned short* __restrict__ uh)
{
    __shared__ float4 wb[2][640];        // 2 x 10,240 B (1 pl each)
    __shared__ float  xl[512];           // [b][p][i]

    const int m  = blockIdx.x / CNT_;
    const int pt = blockIdx.x % CNT_;
    const int p0 = pt * CPT_;
    const int t  = threadIdx.x;
    const int g  = t % 40;
    const int bq = t / 40;
    const int wl = t & ~63;              // wave-uniform slot base

    if (t < 128) {
        int b = t >> 2, q = t & 3;       // p = q>>1, half = q&1
        *(float4*)(xl + b * 16 + q * 4) =
            *(const float4*)(x + (((size_t)b * M_ + m) * P_ + p0 + (q >> 1)) * I_
                             + (q & 1) * 4);
    }
    {   // prologue: stage pl=0 (640 slots in 2 rounds)
        const float* ws0 = W + (size_t)(m * P_ + p0) * 2560;
        #pragma unroll
        for (int q = 0; q < 2; q++) {
            int s = q * 320 + t;
            gload16(ws0 + (size_t)(s ^ ((s >> 4) & 7)) * 4,
                    (float*)&wb[0][q * 320 + wl]);
        }
    }
    __syncthreads();

    #pragma unroll
    for (int h = 0; h < 2; h++) {
        if (h == 0) {                    // prefetch pl=1
            const float* ws1 = W + (size_t)(m * P_ + p0 + 1) * 2560;
            #pragma unroll
            for (int q = 0; q < 2; q++) {
                int s = q * 320 + t;
                gload16(ws1 + (size_t)(s ^ ((s >> 4) & 7)) * 4,
                        (float*)&wb[1][q * 320 + wl]);
            }
        }
        const int pl = h;
        float xr[4][8];
        #pragma unroll
        for (int bb = 0; bb < 4; bb++) {
            *(float4*)(xr[bb])     = *(float4*)(xl + (bq * 4 + bb) * 16 + pl * 8);
            *(float4*)(xr[bb] + 4) = *(float4*)(xl + (bq * 4 + bb) * 16 + pl * 8 + 4);
        }
        const float4* wp = wb[h];
        #pragma unroll
        for (int r = 0; r < 4; r++) {
            const int gb = 4 * g + 160 * r;
            const int hx = (gb >> 4) & 7;
            float4 w0 = wp[(gb + 0) ^ hx];
            float4 w1 = wp[(gb + 1) ^ hx];
            float4 w2 = wp[(gb + 2) ^ hx];
            float4 w3 = wp[(gb + 3) ^ hx];
            const int do0 = 2 * g + 80 * r;
            #pragma unroll
            for (int bb = 0; bb < 4; bb++) {
                const float* a = xr[bb];
                float u0 = w0.x * a[0];
                u0 = fmaf(w0.y, a[1], u0); u0 = fmaf(w0.z, a[2], u0);
                u0 = fmaf(w0.w, a[3], u0); u0 = fmaf(w1.x, a[4], u0);
                u0 = fmaf(w1.y, a[5], u0); u0 = fmaf(w1.z, a[6], u0);
                u0 = fmaf(w1.w, a[7], u0);
                float u1 = w2.x * a[0];
                u1 = fmaf(w2.y, a[1], u1); u1 = fmaf(w2.z, a[2], u1);
                u1 = fmaf(w2.w, a[3], u1); u1 = fmaf(w3.x, a[4], u1);
                u1 = fmaf(w3.y, a[5], u1); u1 = fmaf(w3.z, a[6], u1);
                u1 = fmaf(w3.w, a[7], u1);
                *(unsigned int*)(uh + (((size_t)(bq * 4 + bb) * M_ + m) * P_
                                       + p0 + pl) * DO_ + do0) = pk2(u0, u1);
            }
        }
        if (h == 0) __syncthreads();     // buf1 ready; covered by pl0 compute
    }
}

// ---------------- route: one block per (b,m) row of u_hat ----------------
// MODE 0: s1 partial (uniform c). MODE 1: online-softmax s partial (blog=u.v)
// MODE 2: same + c_maps + features. thread: d=t%20, chunk k=t/20 over P.
// uh stream: prefetch-by-1.
template<int MODE>
__global__ __launch_bounds__(320)
void route_k(const unsigned short* __restrict__ uh, const float* __restrict__ vin,
             float* __restrict__ pbm, float* __restrict__ out)
{
    extern __shared__ float sm[];
    float* accL  = sm;               // [320*17]
    float* red   = sm + 320 * 17;    // [16]
    float* blogL = red + 16;         // [3920] (MODE2)
    float* usqL  = blogL + 3920;     // [3920] (MODE2)

    const int blk = blockIdx.x;      // b*32 + m
    const int t = threadIdx.x;
    const int d = t % 20;
    const int k = t / 20;
    const int pstart = k * 12 + (k < 4 ? k : 4);
    const int pcnt   = (k < 4) ? 13 : 12;
    const unsigned short* up = uh + (size_t)blk * ROW_ + d * 16;

    float vreg[16];
    if (MODE) {
        const float* vb = vin + (size_t)(blk >> 5) * DO_;
        #pragma unroll
        for (int o = 0; o < 16; o++) vreg[o] = vb[d * 16 + o];
    }
    float acc[16];
    #pragma unroll
    for (int o = 0; o < 16; o++) acc[o] = 0.f;
    float mloc = -1e30f, Z = 0.f;

    float4 a0 = ((const float4*)(up + (size_t)pstart * DO_))[0];
    float4 a1 = ((const float4*)(up + (size_t)pstart * DO_))[1];

    for (int pp = 0; pp < pcnt; pp++) {
        const int p  = pstart + pp;
        const int pn = pstart + ((pp + 1 < pcnt) ? pp + 1 : pp);
        float4 n0 = ((const float4*)(up + (size_t)pn * DO_))[0];
        float4 n1 = ((const float4*)(up + (size_t)pn * DO_))[1];

        unsigned int ua[8];
        ua[0]=__float_as_uint(a0.x); ua[1]=__float_as_uint(a0.y);
        ua[2]=__float_as_uint(a0.z); ua[3]=__float_as_uint(a0.w);
        ua[4]=__float_as_uint(a1.x); ua[5]=__float_as_uint(a1.y);
        ua[6]=__float_as_uint(a1.z); ua[7]=__float_as_uint(a1.w);
        float u[16];
        #pragma unroll
        for (int q = 0; q < 8; q++) { u[2*q] = bflo(ua[q]); u[2*q+1] = bfhi(ua[q]); }

        if (MODE) {
            float bl = u[0] * vreg[0];
            #pragma unroll
            for (int o = 1; o < 16; o++) bl = fmaf(u[o], vreg[o], bl);
            if (MODE == 2) {
                float us = u[0] * u[0];
                #pragma unroll
                for (int o = 1; o < 16; o++) us = fmaf(u[o], u[o], us);
                blogL[p * D_ + d] = bl;
                usqL[p * D_ + d]  = us;
            }
            if (bl > mloc + 8.f) {           // defer-max rescale (T13)
                float r = __expf(mloc - bl);
                Z *= r;
                #pragma unroll
                for (int o = 0; o < 16; o++) acc[o] *= r;
                mloc = bl;
            }
            float e = __expf(bl - mloc);
            Z += e;
            #pragma unroll
            for (int o = 0; o < 16; o++) acc[o] = fmaf(e, u[o], acc[o]);
        } else {
            #pragma unroll
            for (int o = 0; o < 16; o++) acc[o] += u[o];
        }
        a0 = n0; a1 = n1;
    }

    float f = 1.f, iz = 1.f, mx = 0.f;
    if (MODE) {
        mx = mloc;
        #pragma unroll
        for (int msk = 1; msk < 64; msk <<= 1) mx = fmaxf(mx, __shfl_xor(mx, msk, 64));
        if ((t & 63) == 0) red[t >> 6] = mx;
        __syncthreads();
        mx = fmaxf(fmaxf(fmaxf(red[0], red[1]), fmaxf(red[2], red[3])), red[4]);
        f = __expf(mloc - mx);
        float zz = Z * f;
        #pragma unroll
        for (int msk = 1; msk < 64; msk <<= 1) zz += __shfl_xor(zz, msk, 64);
        if ((t & 63) == 0) red[8 + (t >> 6)] = zz;
        __syncthreads();
        iz = 1.f / (red[8] + red[9] + red[10] + red[11] + red[12]);
    }
    #pragma unroll
    for (int o = 0; o < 16; o++) accL[t * 17 + o] = acc[o] * f;
    __syncthreads();
    {
        const int dd = t >> 4, oo = t & 15;
        float s = 0.f;
        #pragma unroll
        for (int kk = 0; kk < 16; kk++) s += accL[(kk * 20 + dd) * 17 + oo];
        s *= iz;
        pbm[(size_t)blk * DO_ + t] = s;
        if (MODE == 2) out[FEAT_OFF + (size_t)blk * DO_ + t] = s * (1.f / 196.f);
    }
    if (MODE == 2) {
        for (int e = t; e < PD_; e += 320)
            out[CMAPS_OFF + (size_t)blk * PD_ + e] =
                __expf(blogL[e] - mx) * iz * sqrtf(usqL[e]);
    }
}

// ---------------- squash: per b, sum partials over m ----------------
template<int WH>
__global__ __launch_bounds__(320)
void sq2_k(const float* __restrict__ pbm, float* __restrict__ v1,
           float* __restrict__ vs, float* __restrict__ out)
{
    const int b = blockIdx.x, t = threadIdx.x;
    float s = 0.f;
    for (int mi = 0; mi < M_; mi++) s += pbm[((size_t)b * M_ + mi) * DO_ + t];
    if (WH == 0) s *= (1.f / PD_);
    float sq = s * s;
    #pragma unroll
    for (int msk = 1; msk < 16; msk <<= 1) sq += __shfl_xor(sq, msk, 16);
    float vr = (sq / (1.f + sq)) * s * rsqrtf(sq + 1e-9f);
    if (WH == 0) v1[(size_t)b * DO_ + t] = vr;
    if (WH == 1) vs[(size_t)b * DO_ + t] = v1[(size_t)b * DO_ + t] + vr;
    if (WH == 2) out[(size_t)b * DO_ + t] = vr;
}

extern "C" void kernel_launch(void* const* d_in, const int* in_sizes, int n_in,
                              void* d_out, int out_size, void* d_ws, size_t ws_size,
                              hipStream_t stream)
{
    const float* x = (const float*)d_in[0];
    const float* W = (const float*)d_in[1];
    float* out = (float*)d_out;

    unsigned short* uh = (unsigned short*)d_ws;   // bf16 u_hat: 128,450,560 B
    float* fws = (float*)((char*)d_ws + (size_t)64225280 * 2);
    float* pbm = fws;                             // [B][M][DO]
    float* v1  = pbm + (size_t)B_ * M_ * DO_;
    float* vs  = v1 + (size_t)B_ * DO_;

    const size_t LDS_A = (320 * 17 + 16) * sizeof(float);
    const size_t LDS_B = LDS_A + 2 * PD_ * sizeof(float);

    caps_u<<<M_ * CNT_, 320, 0, stream>>>(x, W, uh);

    route_k<0><<<B_ * M_, 320, LDS_A, stream>>>(uh, v1, pbm, out);
    sq2_k<0><<<B_, 320, 0, stream>>>(pbm, v1, vs, out);

    route_k<1><<<B_ * M_, 320, LDS_A, stream>>>(uh, v1, pbm, out);
    sq2_k<1><<<B_, 320, 0, stream>>>(pbm, v1, vs, out);

    route_k<2><<<B_ * M_, 320, LDS_B, stream>>>(uh, vs, pbm, out);
    sq2_k<2><<<B_, 320, 0, stream>>>(pbm, v1, vs, out);
}

// Round 10
// 116.837 us; speedup vs baseline: 2.3980x; 1.0023x over previous
//
#include <hip/hip_runtime.h>
#include <hip/hip_bf16.h>
#include <math.h>

#define B_   32
#define M_   32
#define P_   196
#define D_   20
#define O_   16
#define I_   8
#define DO_  320    // D*O
#define PD_  3920   // P*D
#define ROW_ 62720  // P*DO

#define CMAPS_OFF 10240
#define FEAT_OFF  4024320

__device__ __forceinline__ unsigned int pk2(float lo, float hi) {
    union { __hip_bfloat162 h; unsigned int u; } cv;
    cv.h = __float22bfloat162_rn(make_float2(lo, hi));   // compiler: v_cvt_pk_bf16_f32
    return cv.u;
}
__device__ __forceinline__ float bfhi(unsigned int w) { return __uint_as_float(w & 0xffff0000u); }
__device__ __forceinline__ float bflo(unsigned int w) { return __uint_as_float(w << 16); }

// async global->LDS, 16B per lane; lds ptr must be wave-uniform base
__device__ __forceinline__ void gload16(const float* g, float* l) {
    __builtin_amdgcn_global_load_lds(
        (const __attribute__((address_space(1))) void*)g,
        (__attribute__((address_space(3))) void*)l, 16, 0, 0);
}

// ---------------- K1: u_hat = W.x -> bf16 ----------------
// grid M*98 (p-tiles of 2), 320 threads. LDS 22.5KB -> ~7 blocks/CU.
// W staged per-pl (10KB), double-buffered; one mid-kernel barrier.
// Source-swizzled (s ^ ((s>>4)&7)) so ds reads are ~conflict-free.
// thread: g=t%40 owns do {2g+80r, +1}, r=0..3 ; bq=t/40 owns b = bq*4+bb.
#define CPT_ 2
#define CNT_ 98
__global__ __launch_bounds__(320)
void caps_u(const float* __restrict__ x, const float* __restrict__ W,
            unsigned short* __restrict__ uh)
{
    __shared__ float4 wb[2][640];        // 2 x 10,240 B (1 pl each)
    __shared__ float  xl[512];           // [b][p][i]

    const int m  = blockIdx.x / CNT_;
    const int pt = blockIdx.x % CNT_;
    const int p0 = pt * CPT_;
    const int t  = threadIdx.x;
    const int g  = t % 40;
    const int bq = t / 40;
    const int wl = t & ~63;              // wave-uniform slot base

    if (t < 128) {
        int b = t >> 2, q = t & 3;       // p = q>>1, half = q&1
        *(float4*)(xl + b * 16 + q * 4) =
            *(const float4*)(x + (((size_t)b * M_ + m) * P_ + p0 + (q >> 1)) * I_
                             + (q & 1) * 4);
    }
    {   // prologue: stage pl=0 (640 slots in 2 rounds)
        const float* ws0 = W + (size_t)(m * P_ + p0) * 2560;
        #pragma unroll
        for (int q = 0; q < 2; q++) {
            int s = q * 320 + t;
            gload16(ws0 + (size_t)(s ^ ((s >> 4) & 7)) * 4,
                    (float*)&wb[0][q * 320 + wl]);
        }
    }
    __syncthreads();

    #pragma unroll
    for (int h = 0; h < 2; h++) {
        if (h == 0) {                    // prefetch pl=1
            const float* ws1 = W + (size_t)(m * P_ + p0 + 1) * 2560;
            #pragma unroll
            for (int q = 0; q < 2; q++) {
                int s = q * 320 + t;
                gload16(ws1 + (size_t)(s ^ ((s >> 4) & 7)) * 4,
                        (float*)&wb[1][q * 320 + wl]);
            }
        }
        const int pl = h;
        float xr[4][8];
        #pragma unroll
        for (int bb = 0; bb < 4; bb++) {
            *(float4*)(xr[bb])     = *(float4*)(xl + (bq * 4 + bb) * 16 + pl * 8);
            *(float4*)(xr[bb] + 4) = *(float4*)(xl + (bq * 4 + bb) * 16 + pl * 8 + 4);
        }
        const float4* wp = wb[h];
        #pragma unroll
        for (int r = 0; r < 4; r++) {
            const int gb = 4 * g + 160 * r;
            const int hx = (gb >> 4) & 7;
            float4 w0 = wp[(gb + 0) ^ hx];
            float4 w1 = wp[(gb + 1) ^ hx];
            float4 w2 = wp[(gb + 2) ^ hx];
            float4 w3 = wp[(gb + 3) ^ hx];
            const int do0 = 2 * g + 80 * r;
            #pragma unroll
            for (int bb = 0; bb < 4; bb++) {
                const float* a = xr[bb];
                float u0 = w0.x * a[0];
                u0 = fmaf(w0.y, a[1], u0); u0 = fmaf(w0.z, a[2], u0);
                u0 = fmaf(w0.w, a[3], u0); u0 = fmaf(w1.x, a[4], u0);
                u0 = fmaf(w1.y, a[5], u0); u0 = fmaf(w1.z, a[6], u0);
                u0 = fmaf(w1.w, a[7], u0);
                float u1 = w2.x * a[0];
                u1 = fmaf(w2.y, a[1], u1); u1 = fmaf(w2.z, a[2], u1);
                u1 = fmaf(w2.w, a[3], u1); u1 = fmaf(w3.x, a[4], u1);
                u1 = fmaf(w3.y, a[5], u1); u1 = fmaf(w3.z, a[6], u1);
                u1 = fmaf(w3.w, a[7], u1);
                *(unsigned int*)(uh + (((size_t)(bq * 4 + bb) * M_ + m) * P_
                                       + p0 + pl) * DO_ + do0) = pk2(u0, u1);
            }
        }
        if (h == 0) __syncthreads();     // buf1 ready; covered by pl0 compute
    }
}

// ---------------- route: one block per (b,m) row of u_hat ----------------
// MODE 0: s1 partial (uniform c). MODE 1: online-softmax s partial (blog=u.v)
// MODE 2: same + c_maps + features. thread: d=t%20, chunk k=t/20 over P.
// uh stream: unroll-2, depth-2 prefetch (4 x 16B loads in flight).
template<int MODE>
__global__ __launch_bounds__(320)
void route_k(const unsigned short* __restrict__ uh, const float* __restrict__ vin,
             float* __restrict__ pbm, float* __restrict__ out)
{
    extern __shared__ float sm[];
    float* accL  = sm;               // [320*17]
    float* red   = sm + 320 * 17;    // [16]
    float* blogL = red + 16;         // [3920] (MODE2)
    float* usqL  = blogL + 3920;     // [3920] (MODE2)

    const int blk = blockIdx.x;      // b*32 + m
    const int t = threadIdx.x;
    const int d = t % 20;
    const int k = t / 20;
    const int pstart = k * 12 + (k < 4 ? k : 4);
    const int pcnt   = (k < 4) ? 13 : 12;
    const unsigned short* up = uh + (size_t)blk * ROW_ + d * 16;

    float vreg[16];
    if (MODE) {
        const float* vb = vin + (size_t)(blk >> 5) * DO_;
        #pragma unroll
        for (int o = 0; o < 16; o++) vreg[o] = vb[d * 16 + o];
    }
    float acc[16];
    #pragma unroll
    for (int o = 0; o < 16; o++) acc[o] = 0.f;
    float mloc = -1e30f, Z = 0.f;

    float4 c0a, c0b, c1a, c1b;
    c0a = ((const float4*)(up + (size_t)pstart * DO_))[0];
    c0b = ((const float4*)(up + (size_t)pstart * DO_))[1];
    {
        int p1 = pstart + (pcnt > 1 ? 1 : 0);
        c1a = ((const float4*)(up + (size_t)p1 * DO_))[0];
        c1b = ((const float4*)(up + (size_t)p1 * DO_))[1];
    }

#define PROC(A0, A1, PIDX)                                                    \
    {                                                                         \
        unsigned int ua[8];                                                   \
        ua[0]=__float_as_uint(A0.x); ua[1]=__float_as_uint(A0.y);             \
        ua[2]=__float_as_uint(A0.z); ua[3]=__float_as_uint(A0.w);             \
        ua[4]=__float_as_uint(A1.x); ua[5]=__float_as_uint(A1.y);             \
        ua[6]=__float_as_uint(A1.z); ua[7]=__float_as_uint(A1.w);             \
        float u[16];                                                          \
        _Pragma("unroll")                                                     \
        for (int q = 0; q < 8; q++) { u[2*q] = bflo(ua[q]); u[2*q+1] = bfhi(ua[q]); } \
        if (MODE) {                                                           \
            float bl = u[0] * vreg[0];                                        \
            _Pragma("unroll")                                                 \
            for (int o = 1; o < 16; o++) bl = fmaf(u[o], vreg[o], bl);        \
            if (MODE == 2) {                                                  \
                float us = u[0] * u[0];                                       \
                _Pragma("unroll")                                             \
                for (int o = 1; o < 16; o++) us = fmaf(u[o], u[o], us);       \
                blogL[(PIDX) * D_ + d] = bl;                                  \
                usqL[(PIDX) * D_ + d]  = us;                                  \
            }                                                                 \
            if (bl > mloc + 8.f) {                                            \
                float rr = __expf(mloc - bl);                                 \
                Z *= rr;                                                      \
                _Pragma("unroll")                                             \
                for (int o = 0; o < 16; o++) acc[o] *= rr;                    \
                mloc = bl;                                                    \
            }                                                                 \
            float e = __expf(bl - mloc);                                      \
            Z += e;                                                           \
            _Pragma("unroll")                                                 \
            for (int o = 0; o < 16; o++) acc[o] = fmaf(e, u[o], acc[o]);      \
        } else {                                                              \
            _Pragma("unroll")                                                 \
            for (int o = 0; o < 16; o++) acc[o] += u[o];                      \
        }                                                                     \
    }

    int pp = 0;
    for (; pp + 1 < pcnt; pp += 2) {
        int pn0 = pstart + ((pp + 2 < pcnt) ? pp + 2 : pcnt - 1);
        int pn1 = pstart + ((pp + 3 < pcnt) ? pp + 3 : pcnt - 1);
        float4 n0a = ((const float4*)(up + (size_t)pn0 * DO_))[0];
        float4 n0b = ((const float4*)(up + (size_t)pn0 * DO_))[1];
        float4 n1a = ((const float4*)(up + (size_t)pn1 * DO_))[0];
        float4 n1b = ((const float4*)(up + (size_t)pn1 * DO_))[1];
        PROC(c0a, c0b, pstart + pp);
        PROC(c1a, c1b, pstart + pp + 1);
        c0a = n0a; c0b = n0b; c1a = n1a; c1b = n1b;
    }
    if (pp < pcnt) PROC(c0a, c0b, pstart + pp);
#undef PROC

    float f = 1.f, iz = 1.f, mx = 0.f;
    if (MODE) {
        mx = mloc;
        #pragma unroll
        for (int msk = 1; msk < 64; msk <<= 1) mx = fmaxf(mx, __shfl_xor(mx, msk, 64));
        if ((t & 63) == 0) red[t >> 6] = mx;
        __syncthreads();
        mx = fmaxf(fmaxf(fmaxf(red[0], red[1]), fmaxf(red[2], red[3])), red[4]);
        f = __expf(mloc - mx);
        float zz = Z * f;
        #pragma unroll
        for (int msk = 1; msk < 64; msk <<= 1) zz += __shfl_xor(zz, msk, 64);
        if ((t & 63) == 0) red[8 + (t >> 6)] = zz;
        __syncthreads();
        iz = 1.f / (red[8] + red[9] + red[10] + red[11] + red[12]);
    }
    #pragma unroll
    for (int o = 0; o < 16; o++) accL[t * 17 + o] = acc[o] * f;
    __syncthreads();
    {
        const int dd = t >> 4, oo = t & 15;
        float s = 0.f;
        #pragma unroll
        for (int kk = 0; kk < 16; kk++) s += accL[(kk * 20 + dd) * 17 + oo];
        s *= iz;
        pbm[(size_t)blk * DO_ + t] = s;
        if (MODE == 2) out[FEAT_OFF + (size_t)blk * DO_ + t] = s * (1.f / 196.f);
    }
    if (MODE == 2) {
        for (int e = t; e < PD_; e += 320)
            out[CMAPS_OFF + (size_t)blk * PD_ + e] =
                __expf(blogL[e] - mx) * iz * sqrtf(usqL[e]);
    }
}

// ---------------- squash: per b, sum partials over m ----------------
template<int WH>
__global__ __launch_bounds__(320)
void sq2_k(const float* __restrict__ pbm, float* __restrict__ v1,
           float* __restrict__ vs, float* __restrict__ out)
{
    const int b = blockIdx.x, t = threadIdx.x;
    float s = 0.f;
    for (int mi = 0; mi < M_; mi++) s += pbm[((size_t)b * M_ + mi) * DO_ + t];
    if (WH == 0) s *= (1.f / PD_);
    float sq = s * s;
    #pragma unroll
    for (int msk = 1; msk < 16; msk <<= 1) sq += __shfl_xor(sq, msk, 16);
    float vr = (sq / (1.f + sq)) * s * rsqrtf(sq + 1e-9f);
    if (WH == 0) v1[(size_t)b * DO_ + t] = vr;
    if (WH == 1) vs[(size_t)b * DO_ + t] = v1[(size_t)b * DO_ + t] + vr;
    if (WH == 2) out[(size_t)b * DO_ + t] = vr;
}

extern "C" void kernel_launch(void* const* d_in, const int* in_sizes, int n_in,
                              void* d_out, int out_size, void* d_ws, size_t ws_size,
                              hipStream_t stream)
{
    const float* x = (const float*)d_in[0];
    const float* W = (const float*)d_in[1];
    float* out = (float*)d_out;

    unsigned short* uh = (unsigned short*)d_ws;   // bf16 u_hat: 128,450,560 B
    float* fws = (float*)((char*)d_ws + (size_t)64225280 * 2);
    float* pbm = fws;                             // [B][M][DO]
    float* v1  = pbm + (size_t)B_ * M_ * DO_;
    float* vs  = v1 + (size_t)B_ * DO_;

    const size_t LDS_A = (320 * 17 + 16) * sizeof(float);
    const size_t LDS_B = LDS_A + 2 * PD_ * sizeof(float);

    caps_u<<<M_ * CNT_, 320, 0, stream>>>(x, W, uh);

    route_k<0><<<B_ * M_, 320, LDS_A, stream>>>(uh, v1, pbm, out);
    sq2_k<0><<<B_, 320, 0, stream>>>(pbm, v1, vs, out);

    route_k<1><<<B_ * M_, 320, LDS_A, stream>>>(uh, v1, pbm, out);
    sq2_k<1><<<B_, 320, 0, stream>>>(pbm, v1, vs, out);

    route_k<2><<<B_ * M_, 320, LDS_B, stream>>>(uh, vs, pbm, out);
    sq2_k<2><<<B_, 320, 0, stream>>>(pbm, v1, vs, out);
}

// Round 11
// 114.927 us; speedup vs baseline: 2.4378x; 1.0166x over previous
//
#include <hip/hip_runtime.h>
#include <hip/hip_bf16.h>
#include <math.h>

#define B_   32
#define M_   32
#define P_   196
#define D_   20
#define O_   16
#define I_   8
#define DO_  320    // D*O
#define PD_  3920   // P*D
#define ROW_ 62720  // P*DO

#define CMAPS_OFF 10240
#define FEAT_OFF  4024320

__device__ __forceinline__ unsigned int pk2(float lo, float hi) {
    union { __hip_bfloat162 h; unsigned int u; } cv;
    cv.h = __float22bfloat162_rn(make_float2(lo, hi));
    return cv.u;
}
__device__ __forceinline__ float bfhi(unsigned int w) { return __uint_as_float(w & 0xffff0000u); }
__device__ __forceinline__ float bflo(unsigned int w) { return __uint_as_float(w << 16); }

// async global->LDS, 16B per lane; lds ptr must be wave-uniform base
__device__ __forceinline__ void gload16(const float* g, float* l) {
    __builtin_amdgcn_global_load_lds(
        (const __attribute__((address_space(1))) void*)g,
        (__attribute__((address_space(3))) void*)l, 16, 0, 0);
}

// ---------------- K1: u_hat = W.x -> bf16 (round-9 best, unchanged) --------
#define CPT_ 2
#define CNT_ 98
__global__ __launch_bounds__(320)
void caps_u(const float* __restrict__ x, const float* __restrict__ W,
            unsigned short* __restrict__ uh)
{
    __shared__ float4 wb[2][640];        // 2 x 10,240 B (1 pl each)
    __shared__ float  xl[512];           // [b][p][i]

    const int m  = blockIdx.x / CNT_;
    const int pt = blockIdx.x % CNT_;
    const int p0 = pt * CPT_;
    const int t  = threadIdx.x;
    const int g  = t % 40;
    const int bq = t / 40;
    const int wl = t & ~63;              // wave-uniform slot base

    if (t < 128) {
        int b = t >> 2, q = t & 3;       // p = q>>1, half = q&1
        *(float4*)(xl + b * 16 + q * 4) =
            *(const float4*)(x + (((size_t)b * M_ + m) * P_ + p0 + (q >> 1)) * I_
                             + (q & 1) * 4);
    }
    {   // prologue: stage pl=0
        const float* ws0 = W + (size_t)(m * P_ + p0) * 2560;
        #pragma unroll
        for (int q = 0; q < 2; q++) {
            int s = q * 320 + t;
            gload16(ws0 + (size_t)(s ^ ((s >> 4) & 7)) * 4,
                    (float*)&wb[0][q * 320 + wl]);
        }
    }
    __syncthreads();

    #pragma unroll
    for (int h = 0; h < 2; h++) {
        if (h == 0) {                    // prefetch pl=1
            const float* ws1 = W + (size_t)(m * P_ + p0 + 1) * 2560;
            #pragma unroll
            for (int q = 0; q < 2; q++) {
                int s = q * 320 + t;
                gload16(ws1 + (size_t)(s ^ ((s >> 4) & 7)) * 4,
                        (float*)&wb[1][q * 320 + wl]);
            }
        }
        const int pl = h;
        float xr[4][8];
        #pragma unroll
        for (int bb = 0; bb < 4; bb++) {
            *(float4*)(xr[bb])     = *(float4*)(xl + (bq * 4 + bb) * 16 + pl * 8);
            *(float4*)(xr[bb] + 4) = *(float4*)(xl + (bq * 4 + bb) * 16 + pl * 8 + 4);
        }
        const float4* wp = wb[h];
        #pragma unroll
        for (int r = 0; r < 4; r++) {
            const int gb = 4 * g + 160 * r;
            const int hx = (gb >> 4) & 7;
            float4 w0 = wp[(gb + 0) ^ hx];
            float4 w1 = wp[(gb + 1) ^ hx];
            float4 w2 = wp[(gb + 2) ^ hx];
            float4 w3 = wp[(gb + 3) ^ hx];
            const int do0 = 2 * g + 80 * r;
            #pragma unroll
            for (int bb = 0; bb < 4; bb++) {
                const float* a = xr[bb];
                float u0 = w0.x * a[0];
                u0 = fmaf(w0.y, a[1], u0); u0 = fmaf(w0.z, a[2], u0);
                u0 = fmaf(w0.w, a[3], u0); u0 = fmaf(w1.x, a[4], u0);
                u0 = fmaf(w1.y, a[5], u0); u0 = fmaf(w1.z, a[6], u0);
                u0 = fmaf(w1.w, a[7], u0);
                float u1 = w2.x * a[0];
                u1 = fmaf(w2.y, a[1], u1); u1 = fmaf(w2.z, a[2], u1);
                u1 = fmaf(w2.w, a[3], u1); u1 = fmaf(w3.x, a[4], u1);
                u1 = fmaf(w3.y, a[5], u1); u1 = fmaf(w3.z, a[6], u1);
                u1 = fmaf(w3.w, a[7], u1);
                *(unsigned int*)(uh + (((size_t)(bq * 4 + bb) * M_ + m) * P_
                                       + p0 + pl) * DO_ + do0) = pk2(u0, u1);
            }
        }
        if (h == 0) __syncthreads();
    }
}

// ---------------- route: one block per (b,m) row of u_hat ----------------
// MODE 0: s1 partial (uniform c) -> pbm.
// MODE 1: head computes v1 = squash(sum_m pbm / PD) inline (m==0 block also
//         stores v1 to global); body = online-softmax s2 partial -> pbm.
// MODE 2: head computes v2 = squash(sum_m pbm), vs = v1g + v2; body same +
//         c_maps + features outputs.
template<int MODE>
__global__ __launch_bounds__(320)
void route_k(const unsigned short* __restrict__ uh, const float* __restrict__ pin,
             float* __restrict__ v1g, float* __restrict__ pbm,
             float* __restrict__ out)
{
    extern __shared__ float sm[];
    float* accL  = sm;               // [320*17] (head reuses [0..320) as vL)
    float* red   = sm + 320 * 17;    // [16]
    float* blogL = red + 16;         // [3920] (MODE2)
    float* usqL  = blogL + 3920;     // [3920] (MODE2)

    const int blk = blockIdx.x;      // b*32 + m
    const int b   = blk >> 5;
    const int mm  = blk & 31;
    const int t = threadIdx.x;
    const int d = t % 20;
    const int k = t / 20;
    const int pstart = k * 12 + (k < 4 ? k : 4);
    const int pcnt   = (k < 4) ? 13 : 12;
    const unsigned short* up = uh + (size_t)blk * ROW_ + d * 16;

    float vreg[16];
    if (MODE) {
        // inline squash of previous iteration's partials (redundant per block)
        float s = 0.f;
        #pragma unroll 8
        for (int mi = 0; mi < M_; mi++) s += pin[((size_t)b * M_ + mi) * DO_ + t];
        if (MODE == 1) s *= (1.f / PD_);
        float sq = s * s;
        #pragma unroll
        for (int msk = 1; msk < 16; msk <<= 1) sq += __shfl_xor(sq, msk, 16);
        float vr = (sq / (1.f + sq)) * s * rsqrtf(sq + 1e-9f);
        if (MODE == 2) vr += v1g[b * DO_ + t];           // vs = v1 + v2
        else if (mm == 0) v1g[b * DO_ + t] = vr;         // persist v1
        accL[t] = vr;
        __syncthreads();
        #pragma unroll
        for (int o = 0; o < 16; o++) vreg[o] = accL[d * 16 + o];
        __syncthreads();
    }
    float acc[16];
    #pragma unroll
    for (int o = 0; o < 16; o++) acc[o] = 0.f;
    float mloc = -1e30f, Z = 0.f;

    float4 a0 = ((const float4*)(up + (size_t)pstart * DO_))[0];
    float4 a1 = ((const float4*)(up + (size_t)pstart * DO_))[1];

    for (int pp = 0; pp < pcnt; pp++) {
        const int p  = pstart + pp;
        const int pn = pstart + ((pp + 1 < pcnt) ? pp + 1 : pp);
        float4 n0 = ((const float4*)(up + (size_t)pn * DO_))[0];
        float4 n1 = ((const float4*)(up + (size_t)pn * DO_))[1];

        unsigned int ua[8];
        ua[0]=__float_as_uint(a0.x); ua[1]=__float_as_uint(a0.y);
        ua[2]=__float_as_uint(a0.z); ua[3]=__float_as_uint(a0.w);
        ua[4]=__float_as_uint(a1.x); ua[5]=__float_as_uint(a1.y);
        ua[6]=__float_as_uint(a1.z); ua[7]=__float_as_uint(a1.w);
        float u[16];
        #pragma unroll
        for (int q = 0; q < 8; q++) { u[2*q] = bflo(ua[q]); u[2*q+1] = bfhi(ua[q]); }

        if (MODE) {
            float bl = u[0] * vreg[0];
            #pragma unroll
            for (int o = 1; o < 16; o++) bl = fmaf(u[o], vreg[o], bl);
            if (MODE == 2) {
                float us = u[0] * u[0];
                #pragma unroll
                for (int o = 1; o < 16; o++) us = fmaf(u[o], u[o], us);
                blogL[p * D_ + d] = bl;
                usqL[p * D_ + d]  = us;
            }
            if (bl > mloc + 8.f) {           // defer-max rescale (T13)
                float r = __expf(mloc - bl);
                Z *= r;
                #pragma unroll
                for (int o = 0; o < 16; o++) acc[o] *= r;
                mloc = bl;
            }
            float e = __expf(bl - mloc);
            Z += e;
            #pragma unroll
            for (int o = 0; o < 16; o++) acc[o] = fmaf(e, u[o], acc[o]);
        } else {
            #pragma unroll
            for (int o = 0; o < 16; o++) acc[o] += u[o];
        }
        a0 = n0; a1 = n1;
    }

    float f = 1.f, iz = 1.f, mx = 0.f;
    if (MODE) {
        mx = mloc;
        #pragma unroll
        for (int msk = 1; msk < 64; msk <<= 1) mx = fmaxf(mx, __shfl_xor(mx, msk, 64));
        if ((t & 63) == 0) red[t >> 6] = mx;
        __syncthreads();
        mx = fmaxf(fmaxf(fmaxf(red[0], red[1]), fmaxf(red[2], red[3])), red[4]);
        f = __expf(mloc - mx);
        float zz = Z * f;
        #pragma unroll
        for (int msk = 1; msk < 64; msk <<= 1) zz += __shfl_xor(zz, msk, 64);
        if ((t & 63) == 0) red[8 + (t >> 6)] = zz;
        __syncthreads();
        iz = 1.f / (red[8] + red[9] + red[10] + red[11] + red[12]);
    }
    #pragma unroll
    for (int o = 0; o < 16; o++) accL[t * 17 + o] = acc[o] * f;
    __syncthreads();
    {
        const int dd = t >> 4, oo = t & 15;
        float s = 0.f;
        #pragma unroll
        for (int kk = 0; kk < 16; kk++) s += accL[(kk * 20 + dd) * 17 + oo];
        s *= iz;
        pbm[(size_t)blk * DO_ + t] = s;
        if (MODE == 2) out[FEAT_OFF + (size_t)blk * DO_ + t] = s * (1.f / 196.f);
    }
    if (MODE == 2) {
        for (int e = t; e < PD_; e += 320)
            out[CMAPS_OFF + (size_t)blk * PD_ + e] =
                __expf(blogL[e] - mx) * iz * sqrtf(usqL[e]);
    }
}

// ---------------- final squash: v -> out ----------------
__global__ __launch_bounds__(320)
void sqf_k(const float* __restrict__ pbm, float* __restrict__ out)
{
    const int b = blockIdx.x, t = threadIdx.x;
    float s = 0.f;
    #pragma unroll 8
    for (int mi = 0; mi < M_; mi++) s += pbm[((size_t)b * M_ + mi) * DO_ + t];
    float sq = s * s;
    #pragma unroll
    for (int msk = 1; msk < 16; msk <<= 1) sq += __shfl_xor(sq, msk, 16);
    float vr = (sq / (1.f + sq)) * s * rsqrtf(sq + 1e-9f);
    out[(size_t)b * DO_ + t] = vr;
}

extern "C" void kernel_launch(void* const* d_in, const int* in_sizes, int n_in,
                              void* d_out, int out_size, void* d_ws, size_t ws_size,
                              hipStream_t stream)
{
    const float* x = (const float*)d_in[0];
    const float* W = (const float*)d_in[1];
    float* out = (float*)d_out;

    unsigned short* uh = (unsigned short*)d_ws;   // bf16 u_hat: 128,450,560 B
    float* fws = (float*)((char*)d_ws + (size_t)64225280 * 2);
    float* pbmA = fws;                            // [B][M][DO]
    float* pbmB = pbmA + (size_t)B_ * M_ * DO_;   // [B][M][DO]
    float* v1g  = pbmB + (size_t)B_ * M_ * DO_;   // [B][DO]

    const size_t LDS_A = (320 * 17 + 16) * sizeof(float);
    const size_t LDS_B = LDS_A + 2 * PD_ * sizeof(float);

    caps_u<<<M_ * CNT_, 320, 0, stream>>>(x, W, uh);

    route_k<0><<<B_ * M_, 320, LDS_A, stream>>>(uh, nullptr, v1g, pbmA, out);
    route_k<1><<<B_ * M_, 320, LDS_A, stream>>>(uh, pbmA, v1g, pbmB, out);
    route_k<2><<<B_ * M_, 320, LDS_B, stream>>>(uh, pbmB, v1g, pbmA, out);
    sqf_k<<<B_, 320, 0, stream>>>(pbmA, out);
}

// Round 13
// 114.886 us; speedup vs baseline: 2.4387x; 1.0004x over previous
//
#include <hip/hip_runtime.h>
#include <hip/hip_bf16.h>
#include <math.h>

#define B_   32
#define M_   32
#define P_   196
#define D_   20
#define O_   16
#define I_   8
#define DO_  320    // D*O
#define PD_  3920   // P*D
#define ROW_ 62720  // P*DO

#define CMAPS_OFF 10240
#define FEAT_OFF  4024320

typedef float f2 __attribute__((ext_vector_type(2)));

__device__ __forceinline__ unsigned int pk2(float lo, float hi) {
    union { __hip_bfloat162 h; unsigned int u; } cv;
    cv.h = __float22bfloat162_rn(make_float2(lo, hi));   // v_cvt_pk_bf16_f32
    return cv.u;
}
__device__ __forceinline__ float bfhi(unsigned int w) { return __uint_as_float(w & 0xffff0000u); }
__device__ __forceinline__ float bflo(unsigned int w) { return __uint_as_float(w << 16); }

// packed f32 fma: c = a*b + c (per 32-bit lane-pair; IEEE fma, full f32)
__device__ __forceinline__ f2 pkfma(f2 a, f2 b, f2 c) {
    asm("v_pk_fma_f32 %0, %1, %2, %0" : "+v"(c) : "v"(a), "v"(b));
    return c;
}

// async global->LDS, 16B per lane; lds ptr must be wave-uniform base
__device__ __forceinline__ void gload16(const float* g, float* l) {
    __builtin_amdgcn_global_load_lds(
        (const __attribute__((address_space(1))) void*)g,
        (__attribute__((address_space(3))) void*)l, 16, 0, 0);
}

// ---------------- K1: u_hat = W.x -> bf16 (round-9 best, unchanged) --------
#define CPT_ 2
#define CNT_ 98
__global__ __launch_bounds__(320)
void caps_u(const float* __restrict__ x, const float* __restrict__ W,
            unsigned short* __restrict__ uh)
{
    __shared__ float4 wb[2][640];        // 2 x 10,240 B (1 pl each)
    __shared__ float  xl[512];           // [b][p][i]

    const int m  = blockIdx.x / CNT_;
    const int pt = blockIdx.x % CNT_;
    const int p0 = pt * CPT_;
    const int t  = threadIdx.x;
    const int g  = t % 40;
    const int bq = t / 40;
    const int wl = t & ~63;              // wave-uniform slot base

    if (t < 128) {
        int b = t >> 2, q = t & 3;       // p = q>>1, half = q&1
        *(float4*)(xl + b * 16 + q * 4) =
            *(const float4*)(x + (((size_t)b * M_ + m) * P_ + p0 + (q >> 1)) * I_
                             + (q & 1) * 4);
    }
    {   // prologue: stage pl=0
        const float* ws0 = W + (size_t)(m * P_ + p0) * 2560;
        #pragma unroll
        for (int q = 0; q < 2; q++) {
            int s = q * 320 + t;
            gload16(ws0 + (size_t)(s ^ ((s >> 4) & 7)) * 4,
                    (float*)&wb[0][q * 320 + wl]);
        }
    }
    __syncthreads();

    #pragma unroll
    for (int h = 0; h < 2; h++) {
        if (h == 0) {                    // prefetch pl=1
            const float* ws1 = W + (size_t)(m * P_ + p0 + 1) * 2560;
            #pragma unroll
            for (int q = 0; q < 2; q++) {
                int s = q * 320 + t;
                gload16(ws1 + (size_t)(s ^ ((s >> 4) & 7)) * 4,
                        (float*)&wb[1][q * 320 + wl]);
            }
        }
        const int pl = h;
        float xr[4][8];
        #pragma unroll
        for (int bb = 0; bb < 4; bb++) {
            *(float4*)(xr[bb])     = *(float4*)(xl + (bq * 4 + bb) * 16 + pl * 8);
            *(float4*)(xr[bb] + 4) = *(float4*)(xl + (bq * 4 + bb) * 16 + pl * 8 + 4);
        }
        const float4* wp = wb[h];
        #pragma unroll
        for (int r = 0; r < 4; r++) {
            const int gb = 4 * g + 160 * r;
            const int hx = (gb >> 4) & 7;
            float4 w0 = wp[(gb + 0) ^ hx];
            float4 w1 = wp[(gb + 1) ^ hx];
            float4 w2 = wp[(gb + 2) ^ hx];
            float4 w3 = wp[(gb + 3) ^ hx];
            const int do0 = 2 * g + 80 * r;
            #pragma unroll
            for (int bb = 0; bb < 4; bb++) {
                const float* a = xr[bb];
                float u0 = w0.x * a[0];
                u0 = fmaf(w0.y, a[1], u0); u0 = fmaf(w0.z, a[2], u0);
                u0 = fmaf(w0.w, a[3], u0); u0 = fmaf(w1.x, a[4], u0);
                u0 = fmaf(w1.y, a[5], u0); u0 = fmaf(w1.z, a[6], u0);
                u0 = fmaf(w1.w, a[7], u0);
                float u1 = w2.x * a[0];
                u1 = fmaf(w2.y, a[1], u1); u1 = fmaf(w2.z, a[2], u1);
                u1 = fmaf(w2.w, a[3], u1); u1 = fmaf(w3.x, a[4], u1);
                u1 = fmaf(w3.y, a[5], u1); u1 = fmaf(w3.z, a[6], u1);
                u1 = fmaf(w3.w, a[7], u1);
                *(unsigned int*)(uh + (((size_t)(bq * 4 + bb) * M_ + m) * P_
                                       + p0 + pl) * DO_ + do0) = pk2(u0, u1);
            }
        }
        if (h == 0) __syncthreads();
    }
}

// ---------------- route: one block per (b,m) row of u_hat ----------------
// MODE 0: s1 partial (uniform c) -> pbm.
// MODE 1: head computes v1 = squash(sum_m pin / PD) inline; body online-softmax
// MODE 2: head v2+v1 -> vs; body same + c_maps + features.
// Inner loop: v_pk_fma_f32 (packed f32) for bl/us/acc chains.
template<int MODE>
__global__ __launch_bounds__(320)
void route_k(const unsigned short* __restrict__ uh, const float* __restrict__ pin,
             float* __restrict__ v1g, float* __restrict__ pbm,
             float* __restrict__ out)
{
    extern __shared__ float sm[];
    float* accL  = sm;               // [320*17] (head reuses [0..320) as vL)
    float* red   = sm + 320 * 17;    // [16]
    float* blogL = red + 16;         // [3920] (MODE2)
    float* usqL  = blogL + 3920;     // [3920] (MODE2)

    const int blk = blockIdx.x;      // b*32 + m
    const int b   = blk >> 5;
    const int mm  = blk & 31;
    const int t = threadIdx.x;
    const int d = t % 20;
    const int k = t / 20;
    const int pstart = k * 12 + (k < 4 ? k : 4);
    const int pcnt   = (k < 4) ? 13 : 12;
    const unsigned short* up = uh + (size_t)blk * ROW_ + d * 16;

    f2 v2[8];
    if (MODE) {
        float s = 0.f;
        #pragma unroll 8
        for (int mi = 0; mi < M_; mi++) s += pin[((size_t)b * M_ + mi) * DO_ + t];
        if (MODE == 1) s *= (1.f / PD_);
        float sq = s * s;
        #pragma unroll
        for (int msk = 1; msk < 16; msk <<= 1) sq += __shfl_xor(sq, msk, 16);
        float vr = (sq / (1.f + sq)) * s * rsqrtf(sq + 1e-9f);
        if (MODE == 2) vr += v1g[b * DO_ + t];           // vs = v1 + v2
        else if (mm == 0) v1g[b * DO_ + t] = vr;         // persist v1
        accL[t] = vr;
        __syncthreads();
        const f2* vL2 = (const f2*)(accL + d * 16);      // 8B-aligned
        #pragma unroll
        for (int q = 0; q < 8; q++) v2[q] = vL2[q];
        __syncthreads();
    }
    f2 acc2[8];
    #pragma unroll
    for (int q = 0; q < 8; q++) acc2[q] = (f2){0.f, 0.f};
    float mloc = -1e30f, Z = 0.f;
    const f2 one2 = {1.f, 1.f};

    float4 a0 = ((const float4*)(up + (size_t)pstart * DO_))[0];
    float4 a1 = ((const float4*)(up + (size_t)pstart * DO_))[1];

    for (int pp = 0; pp < pcnt; pp++) {
        const int p  = pstart + pp;
        const int pn = pstart + ((pp + 1 < pcnt) ? pp + 1 : pp);
        float4 n0 = ((const float4*)(up + (size_t)pn * DO_))[0];
        float4 n1 = ((const float4*)(up + (size_t)pn * DO_))[1];

        unsigned int ua[8];
        ua[0]=__float_as_uint(a0.x); ua[1]=__float_as_uint(a0.y);
        ua[2]=__float_as_uint(a0.z); ua[3]=__float_as_uint(a0.w);
        ua[4]=__float_as_uint(a1.x); ua[5]=__float_as_uint(a1.y);
        ua[6]=__float_as_uint(a1.z); ua[7]=__float_as_uint(a1.w);
        f2 u2[8];
        #pragma unroll
        for (int q = 0; q < 8; q++) u2[q] = (f2){bflo(ua[q]), bfhi(ua[q])};

        if (MODE) {
            f2 blp = {0.f, 0.f};
            #pragma unroll
            for (int q = 0; q < 8; q++) blp = pkfma(u2[q], v2[q], blp);
            float bl = blp.x + blp.y;
            if (MODE == 2) {
                f2 usp = {0.f, 0.f};
                #pragma unroll
                for (int q = 0; q < 8; q++) usp = pkfma(u2[q], u2[q], usp);
                blogL[p * D_ + d] = bl;
                usqL[p * D_ + d]  = usp.x + usp.y;
            }
            if (bl > mloc + 8.f) {           // defer-max rescale (T13)
                float r = __expf(mloc - bl);
                Z *= r;
                f2 r2 = {r, r};
                #pragma unroll
                for (int q = 0; q < 8; q++) acc2[q] = acc2[q] * r2;
                mloc = bl;
            }
            float e = __expf(bl - mloc);
            Z += e;
            f2 e2 = {e, e};
            #pragma unroll
            for (int q = 0; q < 8; q++) acc2[q] = pkfma(u2[q], e2, acc2[q]);
        } else {
            #pragma unroll
            for (int q = 0; q < 8; q++) acc2[q] = pkfma(u2[q], one2, acc2[q]);
        }
        a0 = n0; a1 = n1;
    }

    float f = 1.f, iz = 1.f, mx = 0.f;
    if (MODE) {
        mx = mloc;
        #pragma unroll
        for (int msk = 1; msk < 64; msk <<= 1) mx = fmaxf(mx, __shfl_xor(mx, msk, 64));
        if ((t & 63) == 0) red[t >> 6] = mx;
        __syncthreads();
        mx = fmaxf(fmaxf(fmaxf(red[0], red[1]), fmaxf(red[2], red[3])), red[4]);
        f = __expf(mloc - mx);
        float zz = Z * f;
        #pragma unroll
        for (int msk = 1; msk < 64; msk <<= 1) zz += __shfl_xor(zz, msk, 64);
        if ((t & 63) == 0) red[8 + (t >> 6)] = zz;
        __syncthreads();
        iz = 1.f / (red[8] + red[9] + red[10] + red[11] + red[12]);
    }
    #pragma unroll
    for (int q = 0; q < 8; q++) {
        accL[t * 17 + 2 * q]     = acc2[q].x * f;
        accL[t * 17 + 2 * q + 1] = acc2[q].y * f;
    }
    __syncthreads();
    {
        const int dd = t >> 4, oo = t & 15;
        float s = 0.f;
        #pragma unroll
        for (int kk = 0; kk < 16; kk++) s += accL[(kk * 20 + dd) * 17 + oo];
        s *= iz;
        pbm[(size_t)blk * DO_ + t] = s;
        if (MODE == 2) out[FEAT_OFF + (size_t)blk * DO_ + t] = s * (1.f / 196.f);
    }
    if (MODE == 2) {
        for (int e = t; e < PD_; e += 320)
            out[CMAPS_OFF + (size_t)blk * PD_ + e] =
                __expf(blogL[e] - mx) * iz * sqrtf(usqL[e]);
    }
}

// ---------------- final squash: v -> out ----------------
__global__ __launch_bounds__(320)
void sqf_k(const float* __restrict__ pbm, float* __restrict__ out)
{
    const int b = blockIdx.x, t = threadIdx.x;
    float s = 0.f;
    #pragma unroll 8
    for (int mi = 0; mi < M_; mi++) s += pbm[((size_t)b * M_ + mi) * DO_ + t];
    float sq = s * s;
    #pragma unroll
    for (int msk = 1; msk < 16; msk <<= 1) sq += __shfl_xor(sq, msk, 16);
    float vr = (sq / (1.f + sq)) * s * rsqrtf(sq + 1e-9f);
    out[(size_t)b * DO_ + t] = vr;
}

extern "C" void kernel_launch(void* const* d_in, const int* in_sizes, int n_in,
                              void* d_out, int out_size, void* d_ws, size_t ws_size,
                              hipStream_t stream)
{
    const float* x = (const float*)d_in[0];
    const float* W = (const float*)d_in[1];
    float* out = (float*)d_out;

    unsigned short* uh = (unsigned short*)d_ws;   // bf16 u_hat: 128,450,560 B
    float* fws = (float*)((char*)d_ws + (size_t)64225280 * 2);
    float* pbmA = fws;                            // [B][M][DO]
    float* pbmB = pbmA + (size_t)B_ * M_ * DO_;   // [B][M][DO]
    float* v1g  = pbmB + (size_t)B_ * M_ * DO_;   // [B][DO]

    const size_t LDS_A = (320 * 17 + 16) * sizeof(float);
    const size_t LDS_B = LDS_A + 2 * PD_ * sizeof(float);

    caps_u<<<M_ * CNT_, 320, 0, stream>>>(x, W, uh);

    route_k<0><<<B_ * M_, 320, LDS_A, stream>>>(uh, nullptr, v1g, pbmA, out);
    route_k<1><<<B_ * M_, 320, LDS_A, stream>>>(uh, pbmA, v1g, pbmB, out);
    route_k<2><<<B_ * M_, 320, LDS_B, stream>>>(uh, pbmB, v1g, pbmA, out);
    sqf_k<<<B_, 320, 0, stream>>>(pbmA, out);
}